// Round 16
// baseline (179.823 us; speedup 1.0000x reference)
//
#include <hip/hip_runtime.h>
#include <hip/hip_bf16.h>

// Proto contrastive loss, MI355X. B=2, E=256, HW=1024, C=80, Q=1024.
// SE[p][c] = sum_q exp(dot(featn_p, queue_qc)/TEMP); lse's collapse algebraically.
// Queue rows 0,1 handled in fp32; bf16 GEMM computes rows 2..1023 (|logit|<=1.43).
// v15: bf16 GEMM (i8 reverted after 2 NaN rounds), OCCUPANCY play:
//   wave M-tile 64->32 rows => a[2][8]=64 VGPR + acc[2][4]=32 AGPR (~145/wave)
//   => 3 waves/SIMD (launch_bounds(256,3), cap 170) vs v11's 2 (192/wave).
//   exp2 epilogue (512 cyc/qt trans-pipe) now overlaps MFMA across 12 waves/CU.
//   Block 64x128, grid 2560 (32mt x 80cls, XCD-grouped 10cls/XCD), B dbuf
//   2x16KB (33KB LDS), v9-proven drain sync, zero-C first MFMA, setprio.
// k_prep fuses sm+featn+transpose (v12 verbatim).

#define B_ 2
#define E_ 256
#define HW_ 1024
#define C_ 80
#define Q_ 1024

typedef __attribute__((ext_vector_type(4))) float f32x4;
typedef __attribute__((ext_vector_type(8))) short bf16x8;
typedef unsigned int u32;

#define L2E 1.4426950408889634f
#define SCALE_A (L2E / 0.07f)
#define INV_TEMP (1.0f / 0.07f)

__device__ __forceinline__ ushort f2bf(float f) {
  union { __hip_bfloat16 b; ushort u; } cv;
  cv.b = __float2bfloat16(f);
  return cv.u;
}

__device__ __forceinline__ void gload_lds16(const short* g, short* l) {
  __builtin_amdgcn_global_load_lds(
      (const __attribute__((address_space(1))) void*)g,
      (__attribute__((address_space(3))) void*)l, 16, 0, 0);
}

__device__ __forceinline__ float wred_sum(float v) {
#pragma unroll
  for (int m = 1; m < 64; m <<= 1) v += __shfl_xor(v, m, 64);
  return v;
}

// ---------------- fused prep: transpose (gb<1024) | featn (gb<1088) | sm ----------------
__global__ void k_prep(const float* __restrict__ score, const float* __restrict__ feature,
                       const float* __restrict__ queue, float* __restrict__ SM,
                       float* __restrict__ FEATN, float* __restrict__ NORM,
                       __hip_bfloat16* __restrict__ ABF, __hip_bfloat16* __restrict__ QB,
                       float* __restrict__ CSUM, float* __restrict__ CCNT) {
  __shared__ float smem[8768];
  const int gb = blockIdx.x;
  const int t = threadIdx.x;

  if (gb < 1024) {
    float* ld = smem;                    // 64*81
    int q = gb;
    if (q < B_) {
      bf16x8 z = (bf16x8){0,0,0,0,0,0,0,0};
      for (int i = t; i < C_*E_/8; i += 256) {
        int c = i >> 5, chunk = i & 31;
        *(bf16x8*)(QB + ((size_t)c*Q_ + q)*E_ + chunk*8) = z;
      }
      return;
    }
    const float* src = queue + (size_t)q*E_*C_;
    for (int ec = 0; ec < 4; ec++) {
      for (int i = t; i < 1280; i += 256) {
        float4 v = *(const float4*)(src + (size_t)ec*5120 + (size_t)i*4);
        int row = i / 20, col = (i % 20) * 4;
        ld[row*81 + col + 0] = v.x; ld[row*81 + col + 1] = v.y;
        ld[row*81 + col + 2] = v.z; ld[row*81 + col + 3] = v.w;
      }
      __syncthreads();
#pragma unroll
      for (int pass = 0; pass < 5; pass++) {
        int c = pass*16 + (t >> 4);
        int el = t & 15;
        ushort4 pack;
        pack.x = f2bf(ld[(el*4 + 0)*81 + c]);
        pack.y = f2bf(ld[(el*4 + 1)*81 + c]);
        pack.z = f2bf(ld[(el*4 + 2)*81 + c]);
        pack.w = f2bf(ld[(el*4 + 3)*81 + c]);
        *(ushort4*)(QB + ((size_t)c*Q_ + q)*E_ + ec*64 + el*4) = pack;
      }
      __syncthreads();
    }
    return;
  }

  if (gb < 1088) {
    float* ld = smem;                    // 256*33 = 8448
    float* red = smem + 8448;            // 8*32
    float* istore = smem + 8704;         // 32
    int p0 = (gb - 1024) * 32;
    int b = p0 >> 10, h0 = p0 & 1023;
#pragma unroll
    for (int j = 0; j < 8; j++) {
      int idx = j*256 + t;
      int row = idx >> 3, c4 = idx & 7;
      float4 v = *(const float4*)(feature + ((size_t)(b*E_ + row))*HW_ + h0 + c4*4);
      ld[row*33 + c4*4+0] = v.x; ld[row*33 + c4*4+1] = v.y;
      ld[row*33 + c4*4+2] = v.z; ld[row*33 + c4*4+3] = v.w;
    }
    __syncthreads();
    int px = t & 31, wg = t >> 5;
    float s = 0.f;
    for (int e = wg*32; e < wg*32 + 32; e++) { float v = ld[e*33 + px]; s += v*v; }
    red[wg*32 + px] = s;
    __syncthreads();
    if (t < 32) {
      float ss = 0.f;
#pragma unroll
      for (int g = 0; g < 8; g++) ss += red[g*32 + t];
      float nrm = sqrtf(ss);
      NORM[p0 + t] = nrm;
      istore[t] = 1.0f / fmaxf(nrm, 1e-5f);
    }
    __syncthreads();
#pragma unroll
    for (int j = 0; j < 8; j++) {
      int idx = j*256 + t;
      int wpx = idx >> 6, e4 = idx & 63;
      float iv = istore[wpx];
      float f0 = ld[(e4*4+0)*33 + wpx] * iv;
      float f1 = ld[(e4*4+1)*33 + wpx] * iv;
      float f2 = ld[(e4*4+2)*33 + wpx] * iv;
      float f3 = ld[(e4*4+3)*33 + wpx] * iv;
      float4 o; o.x = f0; o.y = f1; o.z = f2; o.w = f3;
      *(float4*)(FEATN + (size_t)(p0 + wpx)*E_ + e4*4) = o;
      ushort4 pk;
      pk.x = f2bf(f0 * SCALE_A); pk.y = f2bf(f1 * SCALE_A);
      pk.z = f2bf(f2 * SCALE_A); pk.w = f2bf(f3 * SCALE_A);
      *(ushort4*)((ushort*)ABF + (size_t)(p0 + wpx)*E_ + e4*4) = pk;
    }
    return;
  }

  {
    float* ld = smem;                    // 80*33 = 2640
    float* red = smem + 2640;            // 8*32
    float* mstore = smem + 2896;         // 32
    float* istore = smem + 2928;         // 32
    if (gb == 1088 && t < C_) { CSUM[t] = 0.f; CCNT[t] = 0.f; }
    int p0 = (gb - 1088) * 32;
    int b = p0 >> 10, h0 = p0 & 1023;
#pragma unroll
    for (int j = 0; j < 3; j++) {
      int idx = j*256 + t;
      if (idx < 640) {
        int row = idx >> 3, c4 = idx & 7;
        float4 v = *(const float4*)(score + ((size_t)(b*C_ + row))*HW_ + h0 + c4*4);
        ld[row*33 + c4*4+0] = v.x; ld[row*33 + c4*4+1] = v.y;
        ld[row*33 + c4*4+2] = v.z; ld[row*33 + c4*4+3] = v.w;
      }
    }
    __syncthreads();
    int px = t & 31, wg = t >> 5;
    float m = -__builtin_inff();
    for (int c = wg*10; c < wg*10 + 10; c++) m = fmaxf(m, ld[c*33 + px]);
    red[wg*32 + px] = m;
    __syncthreads();
    if (t < 32) {
      float mm = red[t];
#pragma unroll
      for (int g = 1; g < 8; g++) mm = fmaxf(mm, red[g*32 + t]);
      mstore[t] = mm;
    }
    __syncthreads();
    float mf = mstore[px];
    float s = 0.f;
    for (int c = wg*10; c < wg*10 + 10; c++)
      s += __builtin_amdgcn_exp2f((ld[c*33 + px] - mf) * (1000.0f * L2E));
    red[wg*32 + px] = s;
    __syncthreads();
    if (t < 32) {
      float ss = 0.f;
#pragma unroll
      for (int g = 0; g < 8; g++) ss += red[g*32 + t];
      istore[t] = 1.0f / ss;
    }
    __syncthreads();
#pragma unroll
    for (int j = 0; j < 3; j++) {
      int idx = j*256 + t;
      if (idx < 640) {
        int wpx = idx / 20, c4 = idx % 20;
        float mf2 = mstore[wpx], iv = istore[wpx];
        float4 o;
        o.x = __builtin_amdgcn_exp2f((ld[(c4*4+0)*33 + wpx] - mf2) * (1000.0f * L2E)) * iv;
        o.y = __builtin_amdgcn_exp2f((ld[(c4*4+1)*33 + wpx] - mf2) * (1000.0f * L2E)) * iv;
        o.z = __builtin_amdgcn_exp2f((ld[(c4*4+2)*33 + wpx] - mf2) * (1000.0f * L2E)) * iv;
        o.w = __builtin_amdgcn_exp2f((ld[(c4*4+3)*33 + wpx] - mf2) * (1000.0f * L2E)) * iv;
        *(float4*)(SM + (size_t)(p0 + wpx)*C_ + c4*4) = o;
      }
    }
  }
}

// ---------------- prototypes: partial einsum feat * (sm|cm) ----------------
__global__ void k_protos(const float* __restrict__ SM, const float* __restrict__ cmap,
                         const float* __restrict__ FEATN, const float* __restrict__ NORM,
                         float* __restrict__ PART) {
  int hch = blockIdx.x, b = blockIdx.y;
  int map = blockIdx.z >> 1, ch = blockIdx.z & 1;
  int e = threadIdx.x;
  __shared__ float wl[64][40];
  for (int idx = threadIdx.x; idx < 64*40; idx += 256) {
    int ii = idx / 40, cl = idx % 40;
    int c = ch*40 + cl;
    int p = b*HW_ + hch*64 + ii;
    int h = p & 1023;
    float wv = (map == 0) ? SM[(size_t)p*C_ + c] : cmap[((size_t)(b*C_ + c))*HW_ + h];
    wl[ii][cl] = wv * NORM[p];
  }
  __syncthreads();
  float acc[40];
#pragma unroll
  for (int j = 0; j < 40; j++) acc[j] = 0.f;
  for (int ii = 0; ii < 64; ii++) {
    int p = b*HW_ + hch*64 + ii;
    float f = FEATN[(size_t)p*E_ + e];
#pragma unroll
    for (int j = 0; j < 40; j++) acc[j] += f * wl[ii][j];
  }
  float* out = PART + ((size_t)(hch*4 + map*2 + b)*E_ + e)*C_ + ch*40;
#pragma unroll
  for (int j = 0; j < 40; j++) out[j] = acc[j];
}

// reduce 32 chunks -> PROT[map][b][e][c]
__global__ void k_protred(const float* __restrict__ PART, float* __restrict__ PROT) {
  int g = blockIdx.x*256 + threadIdx.x;
  float s = 0.f;
#pragma unroll 8
  for (int chk = 0; chk < 32; chk++) s += PART[(size_t)chk*81920 + g];
  PROT[g] = s;
}

// L2-normalize PROT over e for each (map,b,c)
__global__ void k_norm(float* PROT) {
  int w = threadIdx.x >> 6, l = threadIdx.x & 63;
  int gid = blockIdx.x*4 + w;
  int mb = gid / C_, c = gid % C_;
  float v[4]; float ss = 0.f;
#pragma unroll
  for (int i = 0; i < 4; i++) {
    v[i] = PROT[((size_t)(mb*E_ + l + 64*i))*C_ + c];
    ss += v[i]*v[i];
  }
  ss = wred_sum(ss);
  float inv = 1.0f / fmaxf(sqrtf(ss), 1e-5f);
#pragma unroll
  for (int i = 0; i < 4; i++)
    PROT[((size_t)(mb*E_ + l + 64*i))*C_ + c] = v[i]*inv;
}

// ---------------- main GEMM: SE[p][c] = sum_{q>=2} exp2(acc) + 2 ----------------
// 2560 blocks x 256 thr (4 waves 2Mx2N), wave tile 32x64, block tile 64x128,
// A in registers a[2][8], B dbuf 2x16KB gload_lds, drain sync (v9-proven).
__launch_bounds__(256, 3)
__global__ void k_gemm(const short* __restrict__ A, const short* __restrict__ QB,
                       float* __restrict__ SE) {
  __shared__ short Bs[2][128*64];      // 2 x 16 KB streamed B (swizzled)
  __shared__ float xred[2][2][4][4];   // [wr][mi][fq][j]
  const int tid = threadIdx.x;
  const int l = tid & 63, w = tid >> 6;   // 4 waves
  const int wr = w >> 1, wc = w & 1;      // 2M x 2N
  const int fq = l >> 4, lr = l & 15;
  // XCD grouping: each XCD gets 320 contiguous wids = 10 classes x 32 mt
  int bid = blockIdx.x;
  int wid = (bid & 7) * 320 + (bid >> 3);
  const int mt = wid & 31, cls = wid >> 5;
  const short* Bq = QB + (size_t)cls * (Q_ * E_);

  // ---- A fragments in registers: 32 rows/wave -> a[2][8] = 64 VGPR ----
  bf16x8 a[2][8];
  {
    const short* Ab = A + ((size_t)(mt*64 + wr*32 + lr)) * 256 + fq*8;
#pragma unroll
    for (int mi = 0; mi < 2; mi++)
#pragma unroll
      for (int kk = 0; kk < 8; kk++)
        a[mi][kk] = *(const bf16x8*)(Ab + mi*16*256 + kk*32);
  }

  // slim staging/fragment addressing (swizzle slot fragment-independent)
  const int bg0 = (tid >> 3)*256 + (((tid & 7) ^ ((tid >> 3) & 7)))*8;  // shorts
  const int sA0 = (fq ^ lr) & 7;
  const int sA1 = ((4 + fq) ^ lr) & 7;
  const int Bbase = (wc*64 + lr) * 64;   // shorts

  f32x4 acc[2][4];
  float rs[2][4];
#pragma unroll
  for (int mi = 0; mi < 2; mi++)
#pragma unroll
    for (int j = 0; j < 4; j++) rs[mi][j] = 0.f;
  const f32x4 zacc = (f32x4){0.f, 0.f, 0.f, 0.f};

  // u in [0,32): qt = u>>2 (8 q-tiles of 128), ks = u&3 (4 k-chunks of 64)
#define BSRC(U, I) (Bq + (size_t)((U) >> 2) * 32768 + ((U) & 3) * 64 + bg0 + (I)*8192)
#define STAGEB(U, BUF) { _Pragma("unroll") for (int i = 0; i < 4; i++) \
    gload_lds16(BSRC(U, i), &Bs[BUF][0] + (i*256 + w*64)*8); }

  STAGEB(0, 0);
  __syncthreads();

  for (int u4 = 0; u4 < 8; u4++) {
#pragma unroll
    for (int ks = 0; ks < 4; ks++) {
      const int u = u4*4 + ks;
      const int cur = ks & 1;          // compile-time
      if (u < 31) STAGEB(u+1, cur ^ 1);
      const short* Bcur = &Bs[cur][0] + Bbase;
      __builtin_amdgcn_s_setprio(1);
#pragma unroll
      for (int ksub = 0; ksub < 2; ksub++) {
        const int kk = ks*2 + ksub;    // COMPILE-TIME index into a[][]
        const int sA = ksub ? sA1 : sA0;
        bf16x8 bfr[4];
#pragma unroll
        for (int ni = 0; ni < 4; ni++)
          bfr[ni] = *(const bf16x8*)(Bcur + ni*1024 + sA*8);
        if (kk == 0) {                 // first MFMA of q-tile: C = 0
#pragma unroll
          for (int mi = 0; mi < 2; mi++)
#pragma unroll
            for (int ni = 0; ni < 4; ni++)
              acc[mi][ni] = __builtin_amdgcn_mfma_f32_16x16x32_bf16(a[mi][0], bfr[ni], zacc, 0, 0, 0);
        } else {
#pragma unroll
          for (int mi = 0; mi < 2; mi++)
#pragma unroll
            for (int ni = 0; ni < 4; ni++)
              acc[mi][ni] = __builtin_amdgcn_mfma_f32_16x16x32_bf16(a[mi][kk], bfr[ni], acc[mi][ni], 0, 0, 0);
        }
      }
      __builtin_amdgcn_s_setprio(0);
      if (ks == 3) {                   // q-tile done: exp2 into rs
#pragma unroll
        for (int mi = 0; mi < 2; mi++)
#pragma unroll
          for (int j = 0; j < 4; j++) {
            float s = 0.f;
#pragma unroll
            for (int ni = 0; ni < 4; ni++) s += __builtin_amdgcn_exp2f(acc[mi][ni][j]);
            rs[mi][j] += s;
          }
      }
      __syncthreads();                 // drains vmcnt -> stage(u+1) ready
    }
  }
#undef BSRC
#undef STAGEB

  // class done: reduce across 16 q-columns within wave, then across wc halves
#pragma unroll
  for (int mi = 0; mi < 2; mi++)
#pragma unroll
    for (int j = 0; j < 4; j++) {
      float x = rs[mi][j];
      x += __shfl_xor(x, 1, 64);
      x += __shfl_xor(x, 2, 64);
      x += __shfl_xor(x, 4, 64);
      x += __shfl_xor(x, 8, 64);
      rs[mi][j] = x;
    }
  if (wc == 1 && lr == 0) {
#pragma unroll
    for (int mi = 0; mi < 2; mi++)
#pragma unroll
      for (int j = 0; j < 4; j++) xred[wr][mi][fq][j] = rs[mi][j];
  }
  __syncthreads();
  if (wc == 0 && lr == 0) {
#pragma unroll
    for (int mi = 0; mi < 2; mi++)
#pragma unroll
      for (int j = 0; j < 4; j++) {
        int p = mt*64 + wr*32 + mi*16 + fq*4 + j;
        SE[(size_t)p * C_ + cls] = rs[mi][j] + xred[wr][mi][fq][j];
      }
  }
}

// ---------------- fused pos/neg + masked CE ----------------
__global__ void k_lossf(const float* __restrict__ FEATN, const float* __restrict__ PROT,
                        const float* __restrict__ SE, const float* __restrict__ cmap,
                        float* __restrict__ CSUM, float* __restrict__ CCNT) {
  __shared__ float lf[4][E_];
  int w = threadIdx.x >> 6, l = threadIdx.x & 63;
  int p = blockIdx.x * 4 + w;
  int b = p >> 10, h = p & 1023;
  float4 v = *(const float4*)(FEATN + (size_t)p*E_ + l*4);
  lf[w][l*4+0] = v.x; lf[w][l*4+1] = v.y; lf[w][l*4+2] = v.z; lf[w][l*4+3] = v.w;
  __syncthreads();
  const float* Ppos  = PROT + (size_t)(2 + b)*E_*C_;
  const float* Pneg0 = PROT;
  const float* Pneg1 = PROT + (size_t)E_*C_;
  float ap[2] = {0.f, 0.f}, an0[2] = {0.f, 0.f}, an1[2] = {0.f, 0.f};
#pragma unroll
  for (int part = 0; part < 2; part++) {
    int cc = part*64 + l;
    if (cc < C_) {
      float a = 0.f, n0 = 0.f, n1 = 0.f;
#pragma unroll 8
      for (int e = 0; e < E_; e++) {
        float f = lf[w][e];
        a  += f * Ppos [(size_t)e*C_ + cc];
        n0 += f * Pneg0[(size_t)e*C_ + cc];
        n1 += f * Pneg1[(size_t)e*C_ + cc];
      }
      ap[part] = a * INV_TEMP; an0[part] = n0 * INV_TEMP; an1[part] = n1 * INV_TEMP;
    }
  }
  float pos0    = __shfl(ap[0], 0, 64);
  float n0m1_p0 = __shfl(an0[0], (l + 63) & 63, 64);
  float n0m1_p1 = __shfl(an0[1], (l + 63) & 63, 64);
  float n0_63   = __shfl(an0[0], 63, 64);
  float full0 = SE[(size_t)p*C_ + l] - 2.0f + expf(an0[0]) + expf(an1[0]);
  float full1 = (l < C_ - 64)
              ? SE[(size_t)p*C_ + 64 + l] - 2.0f + expf(an0[1]) + expf(an1[1]) : 0.f;
  float T = wred_sum(full0 + full1);
#pragma unroll
  for (int part = 0; part < 2; part++) {
    int cc = part*64 + l;
    if (cc < C_) {
      float cmv = cmap[((size_t)(b*C_ + cc))*HW_ + h];
      if (cmv > 0.f) {
        float se = part ? full1 : full0;
        float pc = ap[part];
        float tgt = (part == 0) ? ((cc == 0) ? pos0 : n0m1_p0)
                                : ((l == 0) ? n0_63 : n0m1_p1);
        float ce = logf(expf(pc) + (T - se)) - tgt;
        atomicAdd(&CSUM[cc], ce);
        atomicAdd(&CCNT[cc], 1.0f);
      }
    }
  }
}

__global__ void k_final(const float* __restrict__ CSUM, const float* __restrict__ CCNT,
                        float* __restrict__ out) {
  int l = threadIdx.x;
  float s = 0.f;
  for (int c = l; c < C_; c += 64) {
    float cnt = CCNT[c];
    if (cnt > 0.f) s += CSUM[c] / fmaxf(cnt, 1.0f);
  }
  s = wred_sum(s);
  if (l == 0) out[0] = 0.01f * s;
}

// ---------------- workspace layout ----------------
static constexpr size_t OFF_SM    = 0;
static constexpr size_t OFF_PROT  = OFF_SM    + 655360;
static constexpr size_t OFF_FEATN = OFF_PROT  + 327680;
static constexpr size_t OFF_NORM  = OFF_FEATN + 2097152;
static constexpr size_t OFF_ABF   = OFF_NORM  + 8192;
static constexpr size_t OFF_SE    = OFF_ABF   + 1048576;
static constexpr size_t OFF_CSUM  = OFF_SE    + 655360;
static constexpr size_t OFF_CCNT  = OFF_CSUM  + 512;
static constexpr size_t OFF_PART  = OFF_CCNT  + 512;
static constexpr size_t OFF_QB    = OFF_PART  + 10485760;
static constexpr size_t WS_NEED   = OFF_QB    + 41943040;

extern "C" void kernel_launch(void* const* d_in, const int* in_sizes, int n_in,
                              void* d_out, int out_size, void* d_ws, size_t ws_size,
                              hipStream_t stream) {
  (void)in_sizes; (void)n_in; (void)out_size;
  if (ws_size < WS_NEED) return;

  const float* feature = (const float*)d_in[0];
  const float* cmap    = (const float*)d_in[1];
  const float* score   = (const float*)d_in[2];
  const float* queue   = (const float*)d_in[3];
  float* out = (float*)d_out;

  char* ws = (char*)d_ws;
  float* SM    = (float*)(ws + OFF_SM);
  float* PROT  = (float*)(ws + OFF_PROT);
  float* FEATN = (float*)(ws + OFF_FEATN);
  float* NORM  = (float*)(ws + OFF_NORM);
  __hip_bfloat16* ABF = (__hip_bfloat16*)(ws + OFF_ABF);
  float* SE    = (float*)(ws + OFF_SE);
  float* CSUM  = (float*)(ws + OFF_CSUM);
  float* CCNT  = (float*)(ws + OFF_CCNT);
  float* PART  = (float*)(ws + OFF_PART);
  __hip_bfloat16* QB = (__hip_bfloat16*)(ws + OFF_QB);

  k_prep<<<1152, 256, 0, stream>>>(score, feature, queue, SM, FEATN, NORM, ABF, QB, CSUM, CCNT);
  k_protos<<<dim3(32, 2, 4), 256, 0, stream>>>(SM, cmap, FEATN, NORM, PART);
  k_protred<<<320, 256, 0, stream>>>(PART, PROT);
  k_norm<<<80, 256, 0, stream>>>(PROT);
  k_gemm<<<2560, 256, 0, stream>>>((const short*)ABF, (const short*)QB, SE);
  k_lossf<<<512, 256, 0, stream>>>(FEATN, PROT, SE, cmap, CSUM, CCNT);
  k_final<<<1, 64, 0, stream>>>(CSUM, CCNT, out);
}

// Round 18
// 167.099 us; speedup vs baseline: 1.0761x; 1.0761x over previous
//
#include <hip/hip_runtime.h>
#include <hip/hip_bf16.h>

// Proto contrastive loss, MI355X. B=2, E=256, HW=1024, C=80, Q=1024.
// SE[p][c] = sum_q exp(dot(featn_p, queue_qc)/TEMP); lse's collapse algebraically.
// Queue rows 0,1 handled in fp32; bf16 GEMM computes rows 2..1023 (|logit|<=1.43).
// v18 = EXACT round-12 source (best measured: 166.56us, k_gemm 93.5us).
// v17's "revert" had a transcription bug: STAGEB dest (i*512+...) instead of
// (i*256+...) -> chunks i>=2 written 16KB past their buffer -> corrupted B/xred
// -> wrong SE -> log(negative) NaN. This is the verified i*256 version.
// k_gemm: 256-thr, 4 waves 2Mx2N, wave tile 64x64, A-in-reg a[4][8] static kk,
// slim addressing, 4x16KB B buffers, distance-2 counted vmcnt(4), s_barrier,
// setprio. k_prep fuses sm+featn+transpose.

#define B_ 2
#define E_ 256
#define HW_ 1024
#define C_ 80
#define Q_ 1024

typedef __attribute__((ext_vector_type(4))) float f32x4;
typedef __attribute__((ext_vector_type(8))) short bf16x8;
typedef unsigned int u32;

#define L2E 1.4426950408889634f
#define SCALE_A (L2E / 0.07f)
#define INV_TEMP (1.0f / 0.07f)

__device__ __forceinline__ ushort f2bf(float f) {
  union { __hip_bfloat16 b; ushort u; } cv;
  cv.b = __float2bfloat16(f);
  return cv.u;
}

__device__ __forceinline__ void gload_lds16(const short* g, short* l) {
  __builtin_amdgcn_global_load_lds(
      (const __attribute__((address_space(1))) void*)g,
      (__attribute__((address_space(3))) void*)l, 16, 0, 0);
}

__device__ __forceinline__ float wred_sum(float v) {
#pragma unroll
  for (int m = 1; m < 64; m <<= 1) v += __shfl_xor(v, m, 64);
  return v;
}

// ---------------- fused prep: transpose (gb<1024) | featn (gb<1088) | sm ----------------
__global__ void k_prep(const float* __restrict__ score, const float* __restrict__ feature,
                       const float* __restrict__ queue, float* __restrict__ SM,
                       float* __restrict__ FEATN, float* __restrict__ NORM,
                       __hip_bfloat16* __restrict__ ABF, __hip_bfloat16* __restrict__ QB,
                       float* __restrict__ CSUM, float* __restrict__ CCNT) {
  __shared__ float smem[8768];
  const int gb = blockIdx.x;
  const int t = threadIdx.x;

  if (gb < 1024) {
    float* ld = smem;                    // 64*81
    int q = gb;
    if (q < B_) {
      bf16x8 z = (bf16x8){0,0,0,0,0,0,0,0};
      for (int i = t; i < C_*E_/8; i += 256) {
        int c = i >> 5, chunk = i & 31;
        *(bf16x8*)(QB + ((size_t)c*Q_ + q)*E_ + chunk*8) = z;
      }
      return;
    }
    const float* src = queue + (size_t)q*E_*C_;
    for (int ec = 0; ec < 4; ec++) {
      for (int i = t; i < 1280; i += 256) {
        float4 v = *(const float4*)(src + (size_t)ec*5120 + (size_t)i*4);
        int row = i / 20, col = (i % 20) * 4;
        ld[row*81 + col + 0] = v.x; ld[row*81 + col + 1] = v.y;
        ld[row*81 + col + 2] = v.z; ld[row*81 + col + 3] = v.w;
      }
      __syncthreads();
#pragma unroll
      for (int pass = 0; pass < 5; pass++) {
        int c = pass*16 + (t >> 4);
        int el = t & 15;
        ushort4 pack;
        pack.x = f2bf(ld[(el*4 + 0)*81 + c]);
        pack.y = f2bf(ld[(el*4 + 1)*81 + c]);
        pack.z = f2bf(ld[(el*4 + 2)*81 + c]);
        pack.w = f2bf(ld[(el*4 + 3)*81 + c]);
        *(ushort4*)(QB + ((size_t)c*Q_ + q)*E_ + ec*64 + el*4) = pack;
      }
      __syncthreads();
    }
    return;
  }

  if (gb < 1088) {
    float* ld = smem;                    // 256*33 = 8448
    float* red = smem + 8448;            // 8*32
    float* istore = smem + 8704;         // 32
    int p0 = (gb - 1024) * 32;
    int b = p0 >> 10, h0 = p0 & 1023;
#pragma unroll
    for (int j = 0; j < 8; j++) {
      int idx = j*256 + t;
      int row = idx >> 3, c4 = idx & 7;
      float4 v = *(const float4*)(feature + ((size_t)(b*E_ + row))*HW_ + h0 + c4*4);
      ld[row*33 + c4*4+0] = v.x; ld[row*33 + c4*4+1] = v.y;
      ld[row*33 + c4*4+2] = v.z; ld[row*33 + c4*4+3] = v.w;
    }
    __syncthreads();
    int px = t & 31, wg = t >> 5;
    float s = 0.f;
    for (int e = wg*32; e < wg*32 + 32; e++) { float v = ld[e*33 + px]; s += v*v; }
    red[wg*32 + px] = s;
    __syncthreads();
    if (t < 32) {
      float ss = 0.f;
#pragma unroll
      for (int g = 0; g < 8; g++) ss += red[g*32 + t];
      float nrm = sqrtf(ss);
      NORM[p0 + t] = nrm;
      istore[t] = 1.0f / fmaxf(nrm, 1e-5f);
    }
    __syncthreads();
#pragma unroll
    for (int j = 0; j < 8; j++) {
      int idx = j*256 + t;
      int wpx = idx >> 6, e4 = idx & 63;
      float iv = istore[wpx];
      float f0 = ld[(e4*4+0)*33 + wpx] * iv;
      float f1 = ld[(e4*4+1)*33 + wpx] * iv;
      float f2 = ld[(e4*4+2)*33 + wpx] * iv;
      float f3 = ld[(e4*4+3)*33 + wpx] * iv;
      float4 o; o.x = f0; o.y = f1; o.z = f2; o.w = f3;
      *(float4*)(FEATN + (size_t)(p0 + wpx)*E_ + e4*4) = o;
      ushort4 pk;
      pk.x = f2bf(f0 * SCALE_A); pk.y = f2bf(f1 * SCALE_A);
      pk.z = f2bf(f2 * SCALE_A); pk.w = f2bf(f3 * SCALE_A);
      *(ushort4*)((ushort*)ABF + (size_t)(p0 + wpx)*E_ + e4*4) = pk;
    }
    return;
  }

  {
    float* ld = smem;                    // 80*33 = 2640
    float* red = smem + 2640;            // 8*32
    float* mstore = smem + 2896;         // 32
    float* istore = smem + 2928;         // 32
    if (gb == 1088 && t < C_) { CSUM[t] = 0.f; CCNT[t] = 0.f; }
    int p0 = (gb - 1088) * 32;
    int b = p0 >> 10, h0 = p0 & 1023;
#pragma unroll
    for (int j = 0; j < 3; j++) {
      int idx = j*256 + t;
      if (idx < 640) {
        int row = idx >> 3, c4 = idx & 7;
        float4 v = *(const float4*)(score + ((size_t)(b*C_ + row))*HW_ + h0 + c4*4);
        ld[row*33 + c4*4+0] = v.x; ld[row*33 + c4*4+1] = v.y;
        ld[row*33 + c4*4+2] = v.z; ld[row*33 + c4*4+3] = v.w;
      }
    }
    __syncthreads();
    int px = t & 31, wg = t >> 5;
    float m = -__builtin_inff();
    for (int c = wg*10; c < wg*10 + 10; c++) m = fmaxf(m, ld[c*33 + px]);
    red[wg*32 + px] = m;
    __syncthreads();
    if (t < 32) {
      float mm = red[t];
#pragma unroll
      for (int g = 1; g < 8; g++) mm = fmaxf(mm, red[g*32 + t]);
      mstore[t] = mm;
    }
    __syncthreads();
    float mf = mstore[px];
    float s = 0.f;
    for (int c = wg*10; c < wg*10 + 10; c++)
      s += __builtin_amdgcn_exp2f((ld[c*33 + px] - mf) * (1000.0f * L2E));
    red[wg*32 + px] = s;
    __syncthreads();
    if (t < 32) {
      float ss = 0.f;
#pragma unroll
      for (int g = 0; g < 8; g++) ss += red[g*32 + t];
      istore[t] = 1.0f / ss;
    }
    __syncthreads();
#pragma unroll
    for (int j = 0; j < 3; j++) {
      int idx = j*256 + t;
      if (idx < 640) {
        int wpx = idx / 20, c4 = idx % 20;
        float mf2 = mstore[wpx], iv = istore[wpx];
        float4 o;
        o.x = __builtin_amdgcn_exp2f((ld[(c4*4+0)*33 + wpx] - mf2) * (1000.0f * L2E)) * iv;
        o.y = __builtin_amdgcn_exp2f((ld[(c4*4+1)*33 + wpx] - mf2) * (1000.0f * L2E)) * iv;
        o.z = __builtin_amdgcn_exp2f((ld[(c4*4+2)*33 + wpx] - mf2) * (1000.0f * L2E)) * iv;
        o.w = __builtin_amdgcn_exp2f((ld[(c4*4+3)*33 + wpx] - mf2) * (1000.0f * L2E)) * iv;
        *(float4*)(SM + (size_t)(p0 + wpx)*C_ + c4*4) = o;
      }
    }
  }
}

// ---------------- prototypes: partial einsum feat * (sm|cm) ----------------
__global__ void k_protos(const float* __restrict__ SM, const float* __restrict__ cmap,
                         const float* __restrict__ FEATN, const float* __restrict__ NORM,
                         float* __restrict__ PART) {
  int hch = blockIdx.x, b = blockIdx.y;
  int map = blockIdx.z >> 1, ch = blockIdx.z & 1;
  int e = threadIdx.x;
  __shared__ float wl[64][40];
  for (int idx = threadIdx.x; idx < 64*40; idx += 256) {
    int ii = idx / 40, cl = idx % 40;
    int c = ch*40 + cl;
    int p = b*HW_ + hch*64 + ii;
    int h = p & 1023;
    float wv = (map == 0) ? SM[(size_t)p*C_ + c] : cmap[((size_t)(b*C_ + c))*HW_ + h];
    wl[ii][cl] = wv * NORM[p];
  }
  __syncthreads();
  float acc[40];
#pragma unroll
  for (int j = 0; j < 40; j++) acc[j] = 0.f;
  for (int ii = 0; ii < 64; ii++) {
    int p = b*HW_ + hch*64 + ii;
    float f = FEATN[(size_t)p*E_ + e];
#pragma unroll
    for (int j = 0; j < 40; j++) acc[j] += f * wl[ii][j];
  }
  float* out = PART + ((size_t)(hch*4 + map*2 + b)*E_ + e)*C_ + ch*40;
#pragma unroll
  for (int j = 0; j < 40; j++) out[j] = acc[j];
}

// reduce 32 chunks -> PROT[map][b][e][c]
__global__ void k_protred(const float* __restrict__ PART, float* __restrict__ PROT) {
  int g = blockIdx.x*256 + threadIdx.x;
  float s = 0.f;
#pragma unroll 8
  for (int chk = 0; chk < 32; chk++) s += PART[(size_t)chk*81920 + g];
  PROT[g] = s;
}

// L2-normalize PROT over e for each (map,b,c)
__global__ void k_norm(float* PROT) {
  int w = threadIdx.x >> 6, l = threadIdx.x & 63;
  int gid = blockIdx.x*4 + w;
  int mb = gid / C_, c = gid % C_;
  float v[4]; float ss = 0.f;
#pragma unroll
  for (int i = 0; i < 4; i++) {
    v[i] = PROT[((size_t)(mb*E_ + l + 64*i))*C_ + c];
    ss += v[i]*v[i];
  }
  ss = wred_sum(ss);
  float inv = 1.0f / fmaxf(sqrtf(ss), 1e-5f);
#pragma unroll
  for (int i = 0; i < 4; i++)
    PROT[((size_t)(mb*E_ + l + 64*i))*C_ + c] = v[i]*inv;
}

// ---------------- main GEMM: SE[p][c] = sum_{q>=2} exp2(acc) + 2 ----------------
// 1280 blocks x 256 thr (4 waves 2Mx2N), wave tile 64x64, A in registers,
// B QUAD-buffered gload_lds (4x16KB), counted vmcnt(4) + raw s_barrier.
__launch_bounds__(256, 2)
__global__ void k_gemm(const short* __restrict__ A, const short* __restrict__ QB,
                       float* __restrict__ SE) {
  __shared__ short Bs[4][128*64];      // 4 x 16 KB streamed B (swizzled)
  __shared__ float xred[2][4][4][4];   // [wr][mi][fq][j]
  const int tid = threadIdx.x;
  const int l = tid & 63, w = tid >> 6;   // 4 waves
  const int wr = w >> 1, wc = w & 1;      // 2M x 2N
  const int fq = l >> 4, lr = l & 15;
  // XCD grouping: each XCD gets 160 contiguous wids = 10 classes x 16 mt
  int bid = blockIdx.x;
  int wid = (bid & 7) * 160 + (bid >> 3);
  const int mt = wid & 15, cls = wid >> 4;
  const short* Bq = QB + (size_t)cls * (Q_ * E_);

  // ---- A fragments in registers (static indices only from here on) ----
  bf16x8 a[4][8];
  {
    const short* Ab = A + ((size_t)(mt*128 + wr*64 + lr)) * 256 + fq*8;
#pragma unroll
    for (int mi = 0; mi < 4; mi++)
#pragma unroll
      for (int kk = 0; kk < 8; kk++)
        a[mi][kk] = *(const bf16x8*)(Ab + mi*16*256 + kk*32);
  }

  // ---- SLIM staging addressing ----
  // slot s = i*256+tid: row = i*32 + (tid>>3), cp = tid&7; swizzle slot
  // ((cp^row)&7) is i-independent -> single base + static i*8192.
  const int bg0 = (tid >> 3)*256 + (((tid & 7) ^ (tid >> 3)) & 7)*8;
  // ---- SLIM fragment addressing: sA slot is ni-independent (row&7 == lr&7) ----
  const int sA0 = (fq ^ lr) & 7;
  const int sA1 = ((4 + fq) ^ lr) & 7;
  const int Bbase = (wc*64 + lr) * 64;   // shorts

  f32x4 acc[4][4];
  float rs[4][4];
#pragma unroll
  for (int mi = 0; mi < 4; mi++)
#pragma unroll
    for (int ni = 0; ni < 4; ni++) acc[mi][ni] = (f32x4){0.f,0.f,0.f,0.f};
#pragma unroll
  for (int mi = 0; mi < 4; mi++)
#pragma unroll
    for (int j = 0; j < 4; j++) rs[mi][j] = 0.f;

  // u in [0,32): qt = u>>2 (8 q-tiles of 128), ks = u&3 (4 k-chunks of 64)
#define BSRC(U, I) (Bq + (size_t)((U) >> 2) * 32768 + ((U) & 3) * 64 + bg0 + (I)*8192)
#define STAGEB(U, BUF) { _Pragma("unroll") for (int i = 0; i < 4; i++) \
    gload_lds16(BSRC(U, i), &Bs[0][0] + (BUF)*(128*64) + (i*256 + w*64)*8); }
#define VMCNT4 asm volatile("s_waitcnt vmcnt(4)" ::: "memory")
#define VMCNT0 asm volatile("s_waitcnt vmcnt(0)" ::: "memory")

  STAGEB(0, 0);
  STAGEB(1, 1);
  VMCNT4;                               // buf0 complete (buf1's 4 may fly)
  __builtin_amdgcn_s_barrier();

  for (int u4 = 0; u4 < 8; u4++) {
#pragma unroll
    for (int ks = 0; ks < 4; ks++) {
      const int u = u4*4 + ks;          // cur buffer = ks (compile-time)
      if (u4 < 7 || ks < 2) STAGEB(u+2, (ks+2)&3);
      const short* Bcur = &Bs[ks][0] + Bbase;
      __builtin_amdgcn_s_setprio(1);
#pragma unroll
      for (int ksub = 0; ksub < 2; ksub++) {
        const int kk = ks*2 + ksub;     // COMPILE-TIME index into a[][]
        const int sA = ksub ? sA1 : sA0;
        bf16x8 bfr[4];
#pragma unroll
        for (int ni = 0; ni < 4; ni++)
          bfr[ni] = *(const bf16x8*)(Bcur + ni*1024 + sA*8);   // static ni*2048B ds offset
#pragma unroll
        for (int mi = 0; mi < 4; mi++)
#pragma unroll
          for (int ni = 0; ni < 4; ni++)
            acc[mi][ni] = __builtin_amdgcn_mfma_f32_16x16x32_bf16(a[mi][kk], bfr[ni], acc[mi][ni], 0, 0, 0);
      }
      __builtin_amdgcn_s_setprio(0);
      if (ks == 3) {                    // q-tile done: exp2 into rs, reset acc
#pragma unroll
        for (int mi = 0; mi < 4; mi++)
#pragma unroll
          for (int j = 0; j < 4; j++) {
            float s = 0.f;
#pragma unroll
            for (int ni = 0; ni < 4; ni++) s += __builtin_amdgcn_exp2f(acc[mi][ni][j]);
            rs[mi][j] += s;
#pragma unroll
            for (int ni = 0; ni < 4; ni++) acc[mi][ni][j] = 0.f;
          }
      }
      // counted sync: newest 4 loads (for u+2) stay in flight across the barrier
      if (u4 < 7 || ks < 2) {
        VMCNT4; __builtin_amdgcn_s_barrier();
      } else if (ks == 2) {
        VMCNT0; __builtin_amdgcn_s_barrier();
      }                                  // u==31: no wait needed
    }
  }
#undef BSRC
#undef STAGEB
#undef VMCNT4
#undef VMCNT0

  // class done: reduce across 16 q-columns within wave, then across wc halves
#pragma unroll
  for (int mi = 0; mi < 4; mi++)
#pragma unroll
    for (int j = 0; j < 4; j++) {
      float x = rs[mi][j];
      x += __shfl_xor(x, 1, 64);
      x += __shfl_xor(x, 2, 64);
      x += __shfl_xor(x, 4, 64);
      x += __shfl_xor(x, 8, 64);
      rs[mi][j] = x;
    }
  if (wc == 1 && lr == 0) {
#pragma unroll
    for (int mi = 0; mi < 4; mi++)
#pragma unroll
      for (int j = 0; j < 4; j++) xred[wr][mi][fq][j] = rs[mi][j];
  }
  __syncthreads();
  if (wc == 0 && lr == 0) {
#pragma unroll
    for (int mi = 0; mi < 4; mi++)
#pragma unroll
      for (int j = 0; j < 4; j++) {
        int p = mt*128 + wr*64 + mi*16 + fq*4 + j;
        SE[(size_t)p * C_ + cls] = rs[mi][j] + xred[wr][mi][fq][j];
      }
  }
}

// ---------------- fused pos/neg + masked CE ----------------
__global__ void k_lossf(const float* __restrict__ FEATN, const float* __restrict__ PROT,
                        const float* __restrict__ SE, const float* __restrict__ cmap,
                        float* __restrict__ CSUM, float* __restrict__ CCNT) {
  __shared__ float lf[4][E_];
  int w = threadIdx.x >> 6, l = threadIdx.x & 63;
  int p = blockIdx.x * 4 + w;
  int b = p >> 10, h = p & 1023;
  float4 v = *(const float4*)(FEATN + (size_t)p*E_ + l*4);
  lf[w][l*4+0] = v.x; lf[w][l*4+1] = v.y; lf[w][l*4+2] = v.z; lf[w][l*4+3] = v.w;
  __syncthreads();
  const float* Ppos  = PROT + (size_t)(2 + b)*E_*C_;
  const float* Pneg0 = PROT;
  const float* Pneg1 = PROT + (size_t)E_*C_;
  float ap[2] = {0.f, 0.f}, an0[2] = {0.f, 0.f}, an1[2] = {0.f, 0.f};
#pragma unroll
  for (int part = 0; part < 2; part++) {
    int cc = part*64 + l;
    if (cc < C_) {
      float a = 0.f, n0 = 0.f, n1 = 0.f;
#pragma unroll 8
      for (int e = 0; e < E_; e++) {
        float f = lf[w][e];
        a  += f * Ppos [(size_t)e*C_ + cc];
        n0 += f * Pneg0[(size_t)e*C_ + cc];
        n1 += f * Pneg1[(size_t)e*C_ + cc];
      }
      ap[part] = a * INV_TEMP; an0[part] = n0 * INV_TEMP; an1[part] = n1 * INV_TEMP;
    }
  }
  float pos0    = __shfl(ap[0], 0, 64);
  float n0m1_p0 = __shfl(an0[0], (l + 63) & 63, 64);
  float n0m1_p1 = __shfl(an0[1], (l + 63) & 63, 64);
  float n0_63   = __shfl(an0[0], 63, 64);
  float full0 = SE[(size_t)p*C_ + l] - 2.0f + expf(an0[0]) + expf(an1[0]);
  float full1 = (l < C_ - 64)
              ? SE[(size_t)p*C_ + 64 + l] - 2.0f + expf(an0[1]) + expf(an1[1]) : 0.f;
  float T = wred_sum(full0 + full1);
#pragma unroll
  for (int part = 0; part < 2; part++) {
    int cc = part*64 + l;
    if (cc < C_) {
      float cmv = cmap[((size_t)(b*C_ + cc))*HW_ + h];
      if (cmv > 0.f) {
        float se = part ? full1 : full0;
        float pc = ap[part];
        float tgt = (part == 0) ? ((cc == 0) ? pos0 : n0m1_p0)
                                : ((l == 0) ? n0_63 : n0m1_p1);
        float ce = logf(expf(pc) + (T - se)) - tgt;
        atomicAdd(&CSUM[cc], ce);
        atomicAdd(&CCNT[cc], 1.0f);
      }
    }
  }
}

__global__ void k_final(const float* __restrict__ CSUM, const float* __restrict__ CCNT,
                        float* __restrict__ out) {
  int l = threadIdx.x;
  float s = 0.f;
  for (int c = l; c < C_; c += 64) {
    float cnt = CCNT[c];
    if (cnt > 0.f) s += CSUM[c] / fmaxf(cnt, 1.0f);
  }
  s = wred_sum(s);
  if (l == 0) out[0] = 0.01f * s;
}

// ---------------- workspace layout ----------------
static constexpr size_t OFF_SM    = 0;
static constexpr size_t OFF_PROT  = OFF_SM    + 655360;
static constexpr size_t OFF_FEATN = OFF_PROT  + 327680;
static constexpr size_t OFF_NORM  = OFF_FEATN + 2097152;
static constexpr size_t OFF_ABF   = OFF_NORM  + 8192;
static constexpr size_t OFF_SE    = OFF_ABF   + 1048576;
static constexpr size_t OFF_CSUM  = OFF_SE    + 655360;
static constexpr size_t OFF_CCNT  = OFF_CSUM  + 512;
static constexpr size_t OFF_PART  = OFF_CCNT  + 512;
static constexpr size_t OFF_QB    = OFF_PART  + 10485760;
static constexpr size_t WS_NEED   = OFF_QB    + 41943040;

extern "C" void kernel_launch(void* const* d_in, const int* in_sizes, int n_in,
                              void* d_out, int out_size, void* d_ws, size_t ws_size,
                              hipStream_t stream) {
  (void)in_sizes; (void)n_in; (void)out_size;
  if (ws_size < WS_NEED) return;

  const float* feature = (const float*)d_in[0];
  const float* cmap    = (const float*)d_in[1];
  const float* score   = (const float*)d_in[2];
  const float* queue   = (const float*)d_in[3];
  float* out = (float*)d_out;

  char* ws = (char*)d_ws;
  float* SM    = (float*)(ws + OFF_SM);
  float* PROT  = (float*)(ws + OFF_PROT);
  float* FEATN = (float*)(ws + OFF_FEATN);
  float* NORM  = (float*)(ws + OFF_NORM);
  __hip_bfloat16* ABF = (__hip_bfloat16*)(ws + OFF_ABF);
  float* SE    = (float*)(ws + OFF_SE);
  float* CSUM  = (float*)(ws + OFF_CSUM);
  float* CCNT  = (float*)(ws + OFF_CCNT);
  float* PART  = (float*)(ws + OFF_PART);
  __hip_bfloat16* QB = (__hip_bfloat16*)(ws + OFF_QB);

  k_prep<<<1152, 256, 0, stream>>>(score, feature, queue, SM, FEATN, NORM, ABF, QB, CSUM, CCNT);
  k_protos<<<dim3(32, 2, 4), 256, 0, stream>>>(SM, cmap, FEATN, NORM, PART);
  k_protred<<<320, 256, 0, stream>>>(PART, PROT);
  k_norm<<<80, 256, 0, stream>>>(PROT);
  k_gemm<<<1280, 256, 0, stream>>>((const short*)ABF, (const short*)QB, SE);
  k_lossf<<<512, 256, 0, stream>>>(FEATN, PROT, SE, cmap, CSUM, CCNT);
  k_final<<<1, 64, 0, stream>>>(CSUM, CCNT, out);
}

// Round 20
// 166.498 us; speedup vs baseline: 1.0800x; 1.0036x over previous
//
#include <hip/hip_runtime.h>
#include <hip/hip_bf16.h>

// Proto contrastive loss, MI355X. B=2, E=256, HW=1024, C=80, Q=1024.
// SE[p][c] = sum_q exp(dot(featn_p, queue_qc)/TEMP); lse's collapse algebraically.
// Queue rows 0,1 handled in fp32; bf16 GEMM computes rows 2..1023 (|logit|<=1.43).
// FINAL = v18 (verified twice: 166.56us / 167.10us, k_gemm 93.4us @ 38.6%
// MfmaUtil, absmax 0, tripwire clean). v19's k_norm-fold tripped the harness
// determinism tripwire for ~1us upside - reverted.
// k_gemm: 256-thr, 4 waves 2Mx2N, wave tile 64x64, A-in-reg a[4][8] static kk,
// slim addressing, 4x16KB B buffers, distance-2 counted vmcnt(4), s_barrier,
// setprio. k_prep fuses sm+featn+transpose.

#define B_ 2
#define E_ 256
#define HW_ 1024
#define C_ 80
#define Q_ 1024

typedef __attribute__((ext_vector_type(4))) float f32x4;
typedef __attribute__((ext_vector_type(8))) short bf16x8;
typedef unsigned int u32;

#define L2E 1.4426950408889634f
#define SCALE_A (L2E / 0.07f)
#define INV_TEMP (1.0f / 0.07f)

__device__ __forceinline__ ushort f2bf(float f) {
  union { __hip_bfloat16 b; ushort u; } cv;
  cv.b = __float2bfloat16(f);
  return cv.u;
}

__device__ __forceinline__ void gload_lds16(const short* g, short* l) {
  __builtin_amdgcn_global_load_lds(
      (const __attribute__((address_space(1))) void*)g,
      (__attribute__((address_space(3))) void*)l, 16, 0, 0);
}

__device__ __forceinline__ float wred_sum(float v) {
#pragma unroll
  for (int m = 1; m < 64; m <<= 1) v += __shfl_xor(v, m, 64);
  return v;
}

// ---------------- fused prep: transpose (gb<1024) | featn (gb<1088) | sm ----------------
__global__ void k_prep(const float* __restrict__ score, const float* __restrict__ feature,
                       const float* __restrict__ queue, float* __restrict__ SM,
                       float* __restrict__ FEATN, float* __restrict__ NORM,
                       __hip_bfloat16* __restrict__ ABF, __hip_bfloat16* __restrict__ QB,
                       float* __restrict__ CSUM, float* __restrict__ CCNT) {
  __shared__ float smem[8768];
  const int gb = blockIdx.x;
  const int t = threadIdx.x;

  if (gb < 1024) {
    float* ld = smem;                    // 64*81
    int q = gb;
    if (q < B_) {
      bf16x8 z = (bf16x8){0,0,0,0,0,0,0,0};
      for (int i = t; i < C_*E_/8; i += 256) {
        int c = i >> 5, chunk = i & 31;
        *(bf16x8*)(QB + ((size_t)c*Q_ + q)*E_ + chunk*8) = z;
      }
      return;
    }
    const float* src = queue + (size_t)q*E_*C_;
    for (int ec = 0; ec < 4; ec++) {
      for (int i = t; i < 1280; i += 256) {
        float4 v = *(const float4*)(src + (size_t)ec*5120 + (size_t)i*4);
        int row = i / 20, col = (i % 20) * 4;
        ld[row*81 + col + 0] = v.x; ld[row*81 + col + 1] = v.y;
        ld[row*81 + col + 2] = v.z; ld[row*81 + col + 3] = v.w;
      }
      __syncthreads();
#pragma unroll
      for (int pass = 0; pass < 5; pass++) {
        int c = pass*16 + (t >> 4);
        int el = t & 15;
        ushort4 pack;
        pack.x = f2bf(ld[(el*4 + 0)*81 + c]);
        pack.y = f2bf(ld[(el*4 + 1)*81 + c]);
        pack.z = f2bf(ld[(el*4 + 2)*81 + c]);
        pack.w = f2bf(ld[(el*4 + 3)*81 + c]);
        *(ushort4*)(QB + ((size_t)c*Q_ + q)*E_ + ec*64 + el*4) = pack;
      }
      __syncthreads();
    }
    return;
  }

  if (gb < 1088) {
    float* ld = smem;                    // 256*33 = 8448
    float* red = smem + 8448;            // 8*32
    float* istore = smem + 8704;         // 32
    int p0 = (gb - 1024) * 32;
    int b = p0 >> 10, h0 = p0 & 1023;
#pragma unroll
    for (int j = 0; j < 8; j++) {
      int idx = j*256 + t;
      int row = idx >> 3, c4 = idx & 7;
      float4 v = *(const float4*)(feature + ((size_t)(b*E_ + row))*HW_ + h0 + c4*4);
      ld[row*33 + c4*4+0] = v.x; ld[row*33 + c4*4+1] = v.y;
      ld[row*33 + c4*4+2] = v.z; ld[row*33 + c4*4+3] = v.w;
    }
    __syncthreads();
    int px = t & 31, wg = t >> 5;
    float s = 0.f;
    for (int e = wg*32; e < wg*32 + 32; e++) { float v = ld[e*33 + px]; s += v*v; }
    red[wg*32 + px] = s;
    __syncthreads();
    if (t < 32) {
      float ss = 0.f;
#pragma unroll
      for (int g = 0; g < 8; g++) ss += red[g*32 + t];
      float nrm = sqrtf(ss);
      NORM[p0 + t] = nrm;
      istore[t] = 1.0f / fmaxf(nrm, 1e-5f);
    }
    __syncthreads();
#pragma unroll
    for (int j = 0; j < 8; j++) {
      int idx = j*256 + t;
      int wpx = idx >> 6, e4 = idx & 63;
      float iv = istore[wpx];
      float f0 = ld[(e4*4+0)*33 + wpx] * iv;
      float f1 = ld[(e4*4+1)*33 + wpx] * iv;
      float f2 = ld[(e4*4+2)*33 + wpx] * iv;
      float f3 = ld[(e4*4+3)*33 + wpx] * iv;
      float4 o; o.x = f0; o.y = f1; o.z = f2; o.w = f3;
      *(float4*)(FEATN + (size_t)(p0 + wpx)*E_ + e4*4) = o;
      ushort4 pk;
      pk.x = f2bf(f0 * SCALE_A); pk.y = f2bf(f1 * SCALE_A);
      pk.z = f2bf(f2 * SCALE_A); pk.w = f2bf(f3 * SCALE_A);
      *(ushort4*)((ushort*)ABF + (size_t)(p0 + wpx)*E_ + e4*4) = pk;
    }
    return;
  }

  {
    float* ld = smem;                    // 80*33 = 2640
    float* red = smem + 2640;            // 8*32
    float* mstore = smem + 2896;         // 32
    float* istore = smem + 2928;         // 32
    if (gb == 1088 && t < C_) { CSUM[t] = 0.f; CCNT[t] = 0.f; }
    int p0 = (gb - 1088) * 32;
    int b = p0 >> 10, h0 = p0 & 1023;
#pragma unroll
    for (int j = 0; j < 3; j++) {
      int idx = j*256 + t;
      if (idx < 640) {
        int row = idx >> 3, c4 = idx & 7;
        float4 v = *(const float4*)(score + ((size_t)(b*C_ + row))*HW_ + h0 + c4*4);
        ld[row*33 + c4*4+0] = v.x; ld[row*33 + c4*4+1] = v.y;
        ld[row*33 + c4*4+2] = v.z; ld[row*33 + c4*4+3] = v.w;
      }
    }
    __syncthreads();
    int px = t & 31, wg = t >> 5;
    float m = -__builtin_inff();
    for (int c = wg*10; c < wg*10 + 10; c++) m = fmaxf(m, ld[c*33 + px]);
    red[wg*32 + px] = m;
    __syncthreads();
    if (t < 32) {
      float mm = red[t];
#pragma unroll
      for (int g = 1; g < 8; g++) mm = fmaxf(mm, red[g*32 + t]);
      mstore[t] = mm;
    }
    __syncthreads();
    float mf = mstore[px];
    float s = 0.f;
    for (int c = wg*10; c < wg*10 + 10; c++)
      s += __builtin_amdgcn_exp2f((ld[c*33 + px] - mf) * (1000.0f * L2E));
    red[wg*32 + px] = s;
    __syncthreads();
    if (t < 32) {
      float ss = 0.f;
#pragma unroll
      for (int g = 0; g < 8; g++) ss += red[g*32 + t];
      istore[t] = 1.0f / ss;
    }
    __syncthreads();
#pragma unroll
    for (int j = 0; j < 3; j++) {
      int idx = j*256 + t;
      if (idx < 640) {
        int wpx = idx / 20, c4 = idx % 20;
        float mf2 = mstore[wpx], iv = istore[wpx];
        float4 o;
        o.x = __builtin_amdgcn_exp2f((ld[(c4*4+0)*33 + wpx] - mf2) * (1000.0f * L2E)) * iv;
        o.y = __builtin_amdgcn_exp2f((ld[(c4*4+1)*33 + wpx] - mf2) * (1000.0f * L2E)) * iv;
        o.z = __builtin_amdgcn_exp2f((ld[(c4*4+2)*33 + wpx] - mf2) * (1000.0f * L2E)) * iv;
        o.w = __builtin_amdgcn_exp2f((ld[(c4*4+3)*33 + wpx] - mf2) * (1000.0f * L2E)) * iv;
        *(float4*)(SM + (size_t)(p0 + wpx)*C_ + c4*4) = o;
      }
    }
  }
}

// ---------------- prototypes: partial einsum feat * (sm|cm) ----------------
__global__ void k_protos(const float* __restrict__ SM, const float* __restrict__ cmap,
                         const float* __restrict__ FEATN, const float* __restrict__ NORM,
                         float* __restrict__ PART) {
  int hch = blockIdx.x, b = blockIdx.y;
  int map = blockIdx.z >> 1, ch = blockIdx.z & 1;
  int e = threadIdx.x;
  __shared__ float wl[64][40];
  for (int idx = threadIdx.x; idx < 64*40; idx += 256) {
    int ii = idx / 40, cl = idx % 40;
    int c = ch*40 + cl;
    int p = b*HW_ + hch*64 + ii;
    int h = p & 1023;
    float wv = (map == 0) ? SM[(size_t)p*C_ + c] : cmap[((size_t)(b*C_ + c))*HW_ + h];
    wl[ii][cl] = wv * NORM[p];
  }
  __syncthreads();
  float acc[40];
#pragma unroll
  for (int j = 0; j < 40; j++) acc[j] = 0.f;
  for (int ii = 0; ii < 64; ii++) {
    int p = b*HW_ + hch*64 + ii;
    float f = FEATN[(size_t)p*E_ + e];
#pragma unroll
    for (int j = 0; j < 40; j++) acc[j] += f * wl[ii][j];
  }
  float* out = PART + ((size_t)(hch*4 + map*2 + b)*E_ + e)*C_ + ch*40;
#pragma unroll
  for (int j = 0; j < 40; j++) out[j] = acc[j];
}

// reduce 32 chunks -> PROT[map][b][e][c]
__global__ void k_protred(const float* __restrict__ PART, float* __restrict__ PROT) {
  int g = blockIdx.x*256 + threadIdx.x;
  float s = 0.f;
#pragma unroll 8
  for (int chk = 0; chk < 32; chk++) s += PART[(size_t)chk*81920 + g];
  PROT[g] = s;
}

// L2-normalize PROT over e for each (map,b,c)
__global__ void k_norm(float* PROT) {
  int w = threadIdx.x >> 6, l = threadIdx.x & 63;
  int gid = blockIdx.x*4 + w;
  int mb = gid / C_, c = gid % C_;
  float v[4]; float ss = 0.f;
#pragma unroll
  for (int i = 0; i < 4; i++) {
    v[i] = PROT[((size_t)(mb*E_ + l + 64*i))*C_ + c];
    ss += v[i]*v[i];
  }
  ss = wred_sum(ss);
  float inv = 1.0f / fmaxf(sqrtf(ss), 1e-5f);
#pragma unroll
  for (int i = 0; i < 4; i++)
    PROT[((size_t)(mb*E_ + l + 64*i))*C_ + c] = v[i]*inv;
}

// ---------------- main GEMM: SE[p][c] = sum_{q>=2} exp2(acc) + 2 ----------------
// 1280 blocks x 256 thr (4 waves 2Mx2N), wave tile 64x64, A in registers,
// B QUAD-buffered gload_lds (4x16KB), counted vmcnt(4) + raw s_barrier.
__launch_bounds__(256, 2)
__global__ void k_gemm(const short* __restrict__ A, const short* __restrict__ QB,
                       float* __restrict__ SE) {
  __shared__ short Bs[4][128*64];      // 4 x 16 KB streamed B (swizzled)
  __shared__ float xred[2][4][4][4];   // [wr][mi][fq][j]
  const int tid = threadIdx.x;
  const int l = tid & 63, w = tid >> 6;   // 4 waves
  const int wr = w >> 1, wc = w & 1;      // 2M x 2N
  const int fq = l >> 4, lr = l & 15;
  // XCD grouping: each XCD gets 160 contiguous wids = 10 classes x 16 mt
  int bid = blockIdx.x;
  int wid = (bid & 7) * 160 + (bid >> 3);
  const int mt = wid & 15, cls = wid >> 4;
  const short* Bq = QB + (size_t)cls * (Q_ * E_);

  // ---- A fragments in registers (static indices only from here on) ----
  bf16x8 a[4][8];
  {
    const short* Ab = A + ((size_t)(mt*128 + wr*64 + lr)) * 256 + fq*8;
#pragma unroll
    for (int mi = 0; mi < 4; mi++)
#pragma unroll
      for (int kk = 0; kk < 8; kk++)
        a[mi][kk] = *(const bf16x8*)(Ab + mi*16*256 + kk*32);
  }

  // ---- SLIM staging addressing ----
  // slot s = i*256+tid: row = i*32 + (tid>>3), cp = tid&7; swizzle slot
  // ((cp^row)&7) is i-independent -> single base + static i*8192.
  const int bg0 = (tid >> 3)*256 + (((tid & 7) ^ (tid >> 3)) & 7)*8;
  // ---- SLIM fragment addressing: sA slot is ni-independent (row&7 == lr&7) ----
  const int sA0 = (fq ^ lr) & 7;
  const int sA1 = ((4 + fq) ^ lr) & 7;
  const int Bbase = (wc*64 + lr) * 64;   // shorts

  f32x4 acc[4][4];
  float rs[4][4];
#pragma unroll
  for (int mi = 0; mi < 4; mi++)
#pragma unroll
    for (int ni = 0; ni < 4; ni++) acc[mi][ni] = (f32x4){0.f,0.f,0.f,0.f};
#pragma unroll
  for (int mi = 0; mi < 4; mi++)
#pragma unroll
    for (int j = 0; j < 4; j++) rs[mi][j] = 0.f;

  // u in [0,32): qt = u>>2 (8 q-tiles of 128), ks = u&3 (4 k-chunks of 64)
#define BSRC(U, I) (Bq + (size_t)((U) >> 2) * 32768 + ((U) & 3) * 64 + bg0 + (I)*8192)
#define STAGEB(U, BUF) { _Pragma("unroll") for (int i = 0; i < 4; i++) \
    gload_lds16(BSRC(U, i), &Bs[0][0] + (BUF)*(128*64) + (i*256 + w*64)*8); }
#define VMCNT4 asm volatile("s_waitcnt vmcnt(4)" ::: "memory")
#define VMCNT0 asm volatile("s_waitcnt vmcnt(0)" ::: "memory")

  STAGEB(0, 0);
  STAGEB(1, 1);
  VMCNT4;                               // buf0 complete (buf1's 4 may fly)
  __builtin_amdgcn_s_barrier();

  for (int u4 = 0; u4 < 8; u4++) {
#pragma unroll
    for (int ks = 0; ks < 4; ks++) {
      const int u = u4*4 + ks;          // cur buffer = ks (compile-time)
      if (u4 < 7 || ks < 2) STAGEB(u+2, (ks+2)&3);
      const short* Bcur = &Bs[ks][0] + Bbase;
      __builtin_amdgcn_s_setprio(1);
#pragma unroll
      for (int ksub = 0; ksub < 2; ksub++) {
        const int kk = ks*2 + ksub;     // COMPILE-TIME index into a[][]
        const int sA = ksub ? sA1 : sA0;
        bf16x8 bfr[4];
#pragma unroll
        for (int ni = 0; ni < 4; ni++)
          bfr[ni] = *(const bf16x8*)(Bcur + ni*1024 + sA*8);   // static ni*2048B ds offset
#pragma unroll
        for (int mi = 0; mi < 4; mi++)
#pragma unroll
          for (int ni = 0; ni < 4; ni++)
            acc[mi][ni] = __builtin_amdgcn_mfma_f32_16x16x32_bf16(a[mi][kk], bfr[ni], acc[mi][ni], 0, 0, 0);
      }
      __builtin_amdgcn_s_setprio(0);
      if (ks == 3) {                    // q-tile done: exp2 into rs, reset acc
#pragma unroll
        for (int mi = 0; mi < 4; mi++)
#pragma unroll
          for (int j = 0; j < 4; j++) {
            float s = 0.f;
#pragma unroll
            for (int ni = 0; ni < 4; ni++) s += __builtin_amdgcn_exp2f(acc[mi][ni][j]);
            rs[mi][j] += s;
#pragma unroll
            for (int ni = 0; ni < 4; ni++) acc[mi][ni][j] = 0.f;
          }
      }
      // counted sync: newest 4 loads (for u+2) stay in flight across the barrier
      if (u4 < 7 || ks < 2) {
        VMCNT4; __builtin_amdgcn_s_barrier();
      } else if (ks == 2) {
        VMCNT0; __builtin_amdgcn_s_barrier();
      }                                  // u==31: no wait needed
    }
  }
#undef BSRC
#undef STAGEB
#undef VMCNT4
#undef VMCNT0

  // class done: reduce across 16 q-columns within wave, then across wc halves
#pragma unroll
  for (int mi = 0; mi < 4; mi++)
#pragma unroll
    for (int j = 0; j < 4; j++) {
      float x = rs[mi][j];
      x += __shfl_xor(x, 1, 64);
      x += __shfl_xor(x, 2, 64);
      x += __shfl_xor(x, 4, 64);
      x += __shfl_xor(x, 8, 64);
      rs[mi][j] = x;
    }
  if (wc == 1 && lr == 0) {
#pragma unroll
    for (int mi = 0; mi < 4; mi++)
#pragma unroll
      for (int j = 0; j < 4; j++) xred[wr][mi][fq][j] = rs[mi][j];
  }
  __syncthreads();
  if (wc == 0 && lr == 0) {
#pragma unroll
    for (int mi = 0; mi < 4; mi++)
#pragma unroll
      for (int j = 0; j < 4; j++) {
        int p = mt*128 + wr*64 + mi*16 + fq*4 + j;
        SE[(size_t)p * C_ + cls] = rs[mi][j] + xred[wr][mi][fq][j];
      }
  }
}

// ---------------- fused pos/neg + masked CE ----------------
__global__ void k_lossf(const float* __restrict__ FEATN, const float* __restrict__ PROT,
                        const float* __restrict__ SE, const float* __restrict__ cmap,
                        float* __restrict__ CSUM, float* __restrict__ CCNT) {
  __shared__ float lf[4][E_];
  int w = threadIdx.x >> 6, l = threadIdx.x & 63;
  int p = blockIdx.x * 4 + w;
  int b = p >> 10, h = p & 1023;
  float4 v = *(const float4*)(FEATN + (size_t)p*E_ + l*4);
  lf[w][l*4+0] = v.x; lf[w][l*4+1] = v.y; lf[w][l*4+2] = v.z; lf[w][l*4+3] = v.w;
  __syncthreads();
  const float* Ppos  = PROT + (size_t)(2 + b)*E_*C_;
  const float* Pneg0 = PROT;
  const float* Pneg1 = PROT + (size_t)E_*C_;
  float ap[2] = {0.f, 0.f}, an0[2] = {0.f, 0.f}, an1[2] = {0.f, 0.f};
#pragma unroll
  for (int part = 0; part < 2; part++) {
    int cc = part*64 + l;
    if (cc < C_) {
      float a = 0.f, n0 = 0.f, n1 = 0.f;
#pragma unroll 8
      for (int e = 0; e < E_; e++) {
        float f = lf[w][e];
        a  += f * Ppos [(size_t)e*C_ + cc];
        n0 += f * Pneg0[(size_t)e*C_ + cc];
        n1 += f * Pneg1[(size_t)e*C_ + cc];
      }
      ap[part] = a * INV_TEMP; an0[part] = n0 * INV_TEMP; an1[part] = n1 * INV_TEMP;
    }
  }
  float pos0    = __shfl(ap[0], 0, 64);
  float n0m1_p0 = __shfl(an0[0], (l + 63) & 63, 64);
  float n0m1_p1 = __shfl(an0[1], (l + 63) & 63, 64);
  float n0_63   = __shfl(an0[0], 63, 64);
  float full0 = SE[(size_t)p*C_ + l] - 2.0f + expf(an0[0]) + expf(an1[0]);
  float full1 = (l < C_ - 64)
              ? SE[(size_t)p*C_ + 64 + l] - 2.0f + expf(an0[1]) + expf(an1[1]) : 0.f;
  float T = wred_sum(full0 + full1);
#pragma unroll
  for (int part = 0; part < 2; part++) {
    int cc = part*64 + l;
    if (cc < C_) {
      float cmv = cmap[((size_t)(b*C_ + cc))*HW_ + h];
      if (cmv > 0.f) {
        float se = part ? full1 : full0;
        float pc = ap[part];
        float tgt = (part == 0) ? ((cc == 0) ? pos0 : n0m1_p0)
                                : ((l == 0) ? n0_63 : n0m1_p1);
        float ce = logf(expf(pc) + (T - se)) - tgt;
        atomicAdd(&CSUM[cc], ce);
        atomicAdd(&CCNT[cc], 1.0f);
      }
    }
  }
}

__global__ void k_final(const float* __restrict__ CSUM, const float* __restrict__ CCNT,
                        float* __restrict__ out) {
  int l = threadIdx.x;
  float s = 0.f;
  for (int c = l; c < C_; c += 64) {
    float cnt = CCNT[c];
    if (cnt > 0.f) s += CSUM[c] / fmaxf(cnt, 1.0f);
  }
  s = wred_sum(s);
  if (l == 0) out[0] = 0.01f * s;
}

// ---------------- workspace layout ----------------
static constexpr size_t OFF_SM    = 0;
static constexpr size_t OFF_PROT  = OFF_SM    + 655360;
static constexpr size_t OFF_FEATN = OFF_PROT  + 327680;
static constexpr size_t OFF_NORM  = OFF_FEATN + 2097152;
static constexpr size_t OFF_ABF   = OFF_NORM  + 8192;
static constexpr size_t OFF_SE    = OFF_ABF   + 1048576;
static constexpr size_t OFF_CSUM  = OFF_SE    + 655360;
static constexpr size_t OFF_CCNT  = OFF_CSUM  + 512;
static constexpr size_t OFF_PART  = OFF_CCNT  + 512;
static constexpr size_t OFF_QB    = OFF_PART  + 10485760;
static constexpr size_t WS_NEED   = OFF_QB    + 41943040;

extern "C" void kernel_launch(void* const* d_in, const int* in_sizes, int n_in,
                              void* d_out, int out_size, void* d_ws, size_t ws_size,
                              hipStream_t stream) {
  (void)in_sizes; (void)n_in; (void)out_size;
  if (ws_size < WS_NEED) return;

  const float* feature = (const float*)d_in[0];
  const float* cmap    = (const float*)d_in[1];
  const float* score   = (const float*)d_in[2];
  const float* queue   = (const float*)d_in[3];
  float* out = (float*)d_out;

  char* ws = (char*)d_ws;
  float* SM    = (float*)(ws + OFF_SM);
  float* PROT  = (float*)(ws + OFF_PROT);
  float* FEATN = (float*)(ws + OFF_FEATN);
  float* NORM  = (float*)(ws + OFF_NORM);
  __hip_bfloat16* ABF = (__hip_bfloat16*)(ws + OFF_ABF);
  float* SE    = (float*)(ws + OFF_SE);
  float* CSUM  = (float*)(ws + OFF_CSUM);
  float* CCNT  = (float*)(ws + OFF_CCNT);
  float* PART  = (float*)(ws + OFF_PART);
  __hip_bfloat16* QB = (__hip_bfloat16*)(ws + OFF_QB);

  k_prep<<<1152, 256, 0, stream>>>(score, feature, queue, SM, FEATN, NORM, ABF, QB, CSUM, CCNT);
  k_protos<<<dim3(32, 2, 4), 256, 0, stream>>>(SM, cmap, FEATN, NORM, PART);
  k_protred<<<320, 256, 0, stream>>>(PART, PROT);
  k_norm<<<80, 256, 0, stream>>>(PROT);
  k_gemm<<<1280, 256, 0, stream>>>((const short*)ABF, (const short*)QB, SE);
  k_lossf<<<512, 256, 0, stream>>>(FEATN, PROT, SE, cmap, CSUM, CCNT);
  k_final<<<1, 64, 0, stream>>>(CSUM, CCNT, out);
}